// Round 9
// baseline (886.600 us; speedup 1.0000x reference)
//
#include <hip/hip_runtime.h>
#include <math.h>

#define VOCAB 50000
#define EE 301
#define DD 25
#define SEQ 128
#define NC 5
#define BROW 768   // Bmat cols (scan-order, zero-padded): col i*28+j = A[i][e][j] (j<25), i*28+25 = W[e][i]
#define NUSE 700   // useful cols: 25 runs x 28 (A-run 25 + q 1 + 2 pad)
#define TROW 704   // T row stride (floats); scan reads i*28 .. i*28+27

// ---------------- Bmat[e][c'] in scan order ----------------
__global__ __launch_bounds__(256) void build_B(
    const float* __restrict__ A, const float* __restrict__ W,
    float* __restrict__ Bmat)
{
    int e = blockIdx.x;
    for (int c = threadIdx.x; c < BROW; c += 256) {
        float v = 0.f;
        if (c < NUSE) {
            int i = c / 28, j = c % 28;
            if (j < 25)       v = A[((size_t)i * EE + e) * DD + j];
            else if (j == 25) v = W[(size_t)e * DD + i];
        }
        Bmat[(size_t)e * BROW + c] = v;
    }
}

// ---------------- T = emb @ Bmat (ascending-k fmaf chain per element) ----------------
// 128x128 tile, 256 threads, 8x8 microtile, split fragments (2-way-max LDS aliasing).
// Output layout == scan layout -> coalesced float4 epilogue (no scatter, no RMW).
__global__ __launch_bounds__(256, 4) void gemm_T(
    const float* __restrict__ emb,   // [VOCAB][301]
    const float* __restrict__ Bmat,  // [301][BROW]
    float* __restrict__ T)           // [VOCAB][TROW]
{
    __shared__ float As[16][132];    // 128m x 16k
    __shared__ float Bs[16][132];    // 16k x 128n
    int tid = threadIdx.x;
    int tx = tid & 15, ty = tid >> 4;
    int n0 = blockIdx.x * 128;       // n in x: sibling n-tiles of one m-band dispatch together
    int m0 = blockIdx.y * 128;

    float acc[8][8];
#pragma unroll
    for (int a = 0; a < 8; ++a)
#pragma unroll
        for (int c = 0; c < 8; ++c) acc[a][c] = 0.f;

    for (int k0 = 0; k0 < EE; k0 += 16) {
        // As staging: k = k0+tx (64B k-runs), m = m0+ty+16*it
#pragma unroll
        for (int it = 0; it < 8; ++it) {
            int ml = ty + 16 * it;
            int m = m0 + ml, k = k0 + tx;
            As[tx][ml] = (m < VOCAB && k < EE) ? emb[(size_t)m * EE + k] : 0.f;
        }
        // Bs staging: float4 over n (BROW rows: in-row, 16B-aligned)
#pragma unroll
        for (int it = 0; it < 2; ++it) {
            int idx = tid + it * 256;        // 0..511
            int kl = idx >> 5, nl = (idx & 31) * 4;
            int k = k0 + kl;
            float4 v = make_float4(0.f, 0.f, 0.f, 0.f);
            if (k < EE)
                v = *(const float4*)(Bmat + (size_t)k * BROW + n0 + nl);
            *(float4*)(&Bs[kl][nl]) = v;
        }
        __syncthreads();
#pragma unroll
        for (int kk = 0; kk < 16; ++kk) {    // global k strictly ascending
            float4 a0 = *(const float4*)&As[kk][ty * 4];
            float4 a1 = *(const float4*)&As[kk][64 + ty * 4];
            float4 b0 = *(const float4*)&Bs[kk][tx * 4];
            float4 b1 = *(const float4*)&Bs[kk][64 + tx * 4];
            float av[8] = {a0.x, a0.y, a0.z, a0.w, a1.x, a1.y, a1.z, a1.w};
            float bv[8] = {b0.x, b0.y, b0.z, b0.w, b1.x, b1.y, b1.z, b1.w};
#pragma unroll
            for (int a = 0; a < 8; ++a)
#pragma unroll
                for (int c = 0; c < 8; ++c)
                    acc[a][c] = fmaf(av[a], bv[c], acc[a][c]);
        }
        __syncthreads();
    }

    // epilogue: coalesced float4 stores, direct (layout already scan-order)
#pragma unroll
    for (int gi = 0; gi < 2; ++gi) {
#pragma unroll
        for (int r = 0; r < 4; ++r) {
            int m = m0 + gi * 64 + ty * 4 + r;
            if (m < VOCAB) {
                float* row = T + (size_t)m * TROW;
#pragma unroll
                for (int gc = 0; gc < 2; ++gc) {
                    int n = n0 + gc * 64 + tx * 4;
                    if (n < TROW) {
                        int a = gi * 4 + r, c = gc * 4;
                        *(float4*)(row + n) = make_float4(
                            acc[a][c], acc[a][c + 1], acc[a][c + 2], acc[a][c + 3]);
                    }
                }
            }
        }
    }
}

// ---------------- scan: frozen R6/R7 numerics, prefetched + shuffle-based ----------------
__global__ __launch_bounds__(256) void rnn_scan_np4(
    const int*   __restrict__ words,  // [B][SEQ]
    const float* __restrict__ T,      // [VOCAB][TROW]
    const float* __restrict__ V,      // [DD][DD]
    const float* __restrict__ bvec,   // [DD]
    const float* __restrict__ outW,   // [NC][DD]
    const float* __restrict__ outB,   // [NC]
    float* __restrict__ out,          // [B][NC]
    int B)
{
    int tid = threadIdx.x;
    int g = tid >> 5, i = tid & 31;
    int b = blockIdx.x * 8 + g;
    bool act = (i < DD) && (b < B);
    int ii = (i < DD) ? i : (DD - 1);
    int bsafe = (b < B) ? b : 0;
    const int* wr = words + (size_t)bsafe * SEQ;

    float Vcol[DD];
#pragma unroll
    for (int j = 0; j < DD; ++j) Vcol[j] = V[j * DD + ii];   // h@V contracts V[j,i]
    float bi = bvec[ii];

    float hr[DD];
#pragma unroll
    for (int j = 0; j < DD; ++j) hr[j] = 0.f;
    hr[DD - 1] = 1.f;                                        // h0 = e_24

    bool sse = ((b & 3) == 0) && ((i & 3) == 0);
    const float* base = T + (size_t)ii * 28;

    float4 cur[7], nxt[7];
    {
        const float* R = base + (size_t)wr[0] * TROW;
#pragma unroll
        for (int u = 0; u < 7; ++u) cur[u] = *(const float4*)(R + u * 4);
    }

    float hnew = 0.f;
    for (int t = 0; t < SEQ; ++t) {
        int wn = wr[(t + 1 < SEQ) ? t + 1 : t];
        const float* Rn = base + (size_t)wn * TROW;
#pragma unroll
        for (int u = 0; u < 7; ++u) nxt[u] = *(const float4*)(Rn + u * 4);

        float Tj[28];
#pragma unroll
        for (int u = 0; u < 7; ++u) {
            Tj[u * 4 + 0] = cur[u].x; Tj[u * 4 + 1] = cur[u].y;
            Tj[u * 4 + 2] = cur[u].z; Tj[u * 4 + 3] = cur[u].w;
        }
        float qv = Tj[25];

        float a;
        if (sse) {
            float p0 = 0.f, p1 = 0.f, p2 = 0.f, p3 = 0.f;
#pragma unroll
            for (int j = 0; j < 24; j += 4) {
                p0 = __fadd_rn(p0, __fmul_rn(Tj[j],     hr[j]));
                p1 = __fadd_rn(p1, __fmul_rn(Tj[j + 1], hr[j + 1]));
                p2 = __fadd_rn(p2, __fmul_rn(Tj[j + 2], hr[j + 2]));
                p3 = __fadd_rn(p3, __fmul_rn(Tj[j + 3], hr[j + 3]));
            }
            float s02 = __fadd_rn(p0, p2);
            float s13 = __fadd_rn(p1, p3);
            a = __fadd_rn(s02, s13);
            a = __fadd_rn(a, __fmul_rn(Tj[24], hr[24]));     // scalar tail j=24
        } else {
            a = 0.f;
#pragma unroll
            for (int j = 0; j < DD; ++j)
                a = __fadd_rn(a, __fmul_rn(Tj[j], hr[j]));
        }

        float r2 = 0.f;                                      // h@V: BLAS k-seq FMA
#pragma unroll
        for (int j = 0; j < DD; ++j)
            r2 = fmaf(hr[j], Vcol[j], r2);

        float lin = __fadd_rn(__fadd_rn(qv, r2), bi);        // (xW + hV) + b
        float pre = __fadd_rn(a, lin);                       // a + lin
        hnew = act ? (float)tanh((double)pre) : 0.f;

#pragma unroll
        for (int j = 0; j < DD; ++j)                          // broadcast h within 32-group
            hr[j] = __shfl(hnew, j, 32);

#pragma unroll
        for (int u = 0; u < 7; ++u) cur[u] = nxt[u];
    }

    // logits = h @ out_W.T + out_b ; sigmoid  (BLAS k-seq FMA)
    if (i < NC && b < B) {
        float acc = 0.f;
#pragma unroll
        for (int j = 0; j < DD; ++j)
            acc = fmaf(hr[j], outW[i * DD + j], acc);
        float l = __fadd_rn(acc, outB[i]);
        out[(size_t)b * NC + i] = (float)(1.0 / (1.0 + exp(-(double)l)));
    }
}

extern "C" void kernel_launch(void* const* d_in, const int* in_sizes, int n_in,
                              void* d_out, int out_size, void* d_ws, size_t ws_size,
                              hipStream_t stream)
{
    const int*   words = (const int*)d_in[0];
    const float* emb   = (const float*)d_in[2];
    const float* A     = (const float*)d_in[3];
    const float* W     = (const float*)d_in[4];
    const float* V     = (const float*)d_in[5];
    const float* bias  = (const float*)d_in[6];
    const float* outW  = (const float*)d_in[7];
    const float* outB  = (const float*)d_in[8];
    float* out = (float*)d_out;
    int B = in_sizes[0] / SEQ;

    float* Bmat = (float*)d_ws;                        // 301*768*4 ≈ 0.92 MB
    float* T    = (float*)((char*)d_ws + (1 << 20));   // 50000*704*4 ≈ 140.8 MB

    build_B<<<EE, 256, 0, stream>>>(A, W, Bmat);
    gemm_T<<<dim3(6, (VOCAB + 127) / 128), 256, 0, stream>>>(emb, Bmat, T);
    rnn_scan_np4<<<(B + 7) / 8, 256, 0, stream>>>(words, T, V, bias, outW, outB, out, B);
}

// Round 10
// 584.080 us; speedup vs baseline: 1.5179x; 1.5179x over previous
//
#include <hip/hip_runtime.h>
#include <math.h>

#define VOCAB 50000
#define EE 301
#define DD 25
#define SEQ 128
#define NC 5
#define BROW 768   // Bmat cols (scan-order, zero-padded): col i*28+j = A[i][e][j] (j<25), i*28+25 = W[e][i]
#define NUSE 700   // useful cols: 25 runs x 28 (A-run 25 + q 1 + 2 pad)
#define TROW 704   // T row stride (floats); scan reads i*28 .. i*28+27

// ---------------- Bmat[e][c'] in scan order ----------------
__global__ __launch_bounds__(256) void build_B(
    const float* __restrict__ A, const float* __restrict__ W,
    float* __restrict__ Bmat)
{
    int e = blockIdx.x;
    for (int c = threadIdx.x; c < BROW; c += 256) {
        float v = 0.f;
        if (c < NUSE) {
            int i = c / 28, j = c % 28;
            if (j < 25)       v = A[((size_t)i * EE + e) * DD + j];
            else if (j == 25) v = W[(size_t)e * DD + i];
        }
        Bmat[(size_t)e * BROW + c] = v;
    }
}

// ---------------- T = emb @ Bmat (ascending-k fmaf chain per element) ----------------
// 128x128 tile, 256 threads, 8x8 microtile, split fragments (2-way-max LDS aliasing).
// launch_bounds(256,2): VGPR budget 256 -> NO spill (R8/R9's (256,4) cap forced scratch
// spills = ~950 MB of fetch+write traffic; that was the 690us regression).
__global__ __launch_bounds__(256, 2) void gemm_T(
    const float* __restrict__ emb,   // [VOCAB][301]
    const float* __restrict__ Bmat,  // [301][BROW]
    float* __restrict__ T)           // [VOCAB][TROW]
{
    __shared__ float As[16][132];    // 128m x 16k
    __shared__ float Bs[16][132];    // 16k x 128n
    int tid = threadIdx.x;
    int tx = tid & 15, ty = tid >> 4;
    int m0 = blockIdx.x * 128;       // m in x (R7 dispatch order: no fetch amplification)
    int n0 = blockIdx.y * 128;

    float acc[8][8];
#pragma unroll
    for (int a = 0; a < 8; ++a)
#pragma unroll
        for (int c = 0; c < 8; ++c) acc[a][c] = 0.f;

    for (int k0 = 0; k0 < EE; k0 += 16) {
        // As staging: k = k0+tx (64B k-runs), m = m0+ty+16*it
#pragma unroll
        for (int it = 0; it < 8; ++it) {
            int ml = ty + 16 * it;
            int m = m0 + ml, k = k0 + tx;
            As[tx][ml] = (m < VOCAB && k < EE) ? emb[(size_t)m * EE + k] : 0.f;
        }
        // Bs staging: float4 over n (BROW rows: in-row, 16B-aligned)
#pragma unroll
        for (int it = 0; it < 2; ++it) {
            int idx = tid + it * 256;        // 0..511
            int kl = idx >> 5, nl = (idx & 31) * 4;
            int k = k0 + kl;
            float4 v = make_float4(0.f, 0.f, 0.f, 0.f);
            if (k < EE)
                v = *(const float4*)(Bmat + (size_t)k * BROW + n0 + nl);
            *(float4*)(&Bs[kl][nl]) = v;
        }
        __syncthreads();
#pragma unroll
        for (int kk = 0; kk < 16; ++kk) {    // global k strictly ascending
            float4 a0 = *(const float4*)&As[kk][ty * 4];
            float4 a1 = *(const float4*)&As[kk][64 + ty * 4];
            float4 b0 = *(const float4*)&Bs[kk][tx * 4];
            float4 b1 = *(const float4*)&Bs[kk][64 + tx * 4];
            float av[8] = {a0.x, a0.y, a0.z, a0.w, a1.x, a1.y, a1.z, a1.w};
            float bv[8] = {b0.x, b0.y, b0.z, b0.w, b1.x, b1.y, b1.z, b1.w};
#pragma unroll
            for (int a = 0; a < 8; ++a)
#pragma unroll
                for (int c = 0; c < 8; ++c)
                    acc[a][c] = fmaf(av[a], bv[c], acc[a][c]);
        }
        __syncthreads();
    }

    // epilogue: coalesced float4 stores, direct (layout already scan-order)
#pragma unroll
    for (int gi = 0; gi < 2; ++gi) {
#pragma unroll
        for (int r = 0; r < 4; ++r) {
            int m = m0 + gi * 64 + ty * 4 + r;
            if (m < VOCAB) {
                float* row = T + (size_t)m * TROW;
#pragma unroll
                for (int gc = 0; gc < 2; ++gc) {
                    int n = n0 + gc * 64 + tx * 4;
                    if (n < TROW) {
                        int a = gi * 4 + r, c = gc * 4;
                        *(float4*)(row + n) = make_float4(
                            acc[a][c], acc[a][c + 1], acc[a][c + 2], acc[a][c + 3]);
                    }
                }
            }
        }
    }
}

// ---------------- scan: frozen R6/R7 numerics, prefetched + shuffle-based ----------------
__global__ __launch_bounds__(256) void rnn_scan_np4(
    const int*   __restrict__ words,  // [B][SEQ]
    const float* __restrict__ T,      // [VOCAB][TROW]
    const float* __restrict__ V,      // [DD][DD]
    const float* __restrict__ bvec,   // [DD]
    const float* __restrict__ outW,   // [NC][DD]
    const float* __restrict__ outB,   // [NC]
    float* __restrict__ out,          // [B][NC]
    int B)
{
    int tid = threadIdx.x;
    int g = tid >> 5, i = tid & 31;
    int b = blockIdx.x * 8 + g;
    bool act = (i < DD) && (b < B);
    int ii = (i < DD) ? i : (DD - 1);
    int bsafe = (b < B) ? b : 0;
    const int* wr = words + (size_t)bsafe * SEQ;

    float Vcol[DD];
#pragma unroll
    for (int j = 0; j < DD; ++j) Vcol[j] = V[j * DD + ii];   // h@V contracts V[j,i]
    float bi = bvec[ii];

    float hr[DD];
#pragma unroll
    for (int j = 0; j < DD; ++j) hr[j] = 0.f;
    hr[DD - 1] = 1.f;                                        // h0 = e_24

    bool sse = ((b & 3) == 0) && ((i & 3) == 0);
    const float* base = T + (size_t)ii * 28;

    float4 cur[7], nxt[7];
    {
        const float* R = base + (size_t)wr[0] * TROW;
#pragma unroll
        for (int u = 0; u < 7; ++u) cur[u] = *(const float4*)(R + u * 4);
    }

    float hnew = 0.f;
    for (int t = 0; t < SEQ; ++t) {
        int wn = wr[(t + 1 < SEQ) ? t + 1 : t];
        const float* Rn = base + (size_t)wn * TROW;
#pragma unroll
        for (int u = 0; u < 7; ++u) nxt[u] = *(const float4*)(Rn + u * 4);

        float Tj[28];
#pragma unroll
        for (int u = 0; u < 7; ++u) {
            Tj[u * 4 + 0] = cur[u].x; Tj[u * 4 + 1] = cur[u].y;
            Tj[u * 4 + 2] = cur[u].z; Tj[u * 4 + 3] = cur[u].w;
        }
        float qv = Tj[25];

        float a;
        if (sse) {
            float p0 = 0.f, p1 = 0.f, p2 = 0.f, p3 = 0.f;
#pragma unroll
            for (int j = 0; j < 24; j += 4) {
                p0 = __fadd_rn(p0, __fmul_rn(Tj[j],     hr[j]));
                p1 = __fadd_rn(p1, __fmul_rn(Tj[j + 1], hr[j + 1]));
                p2 = __fadd_rn(p2, __fmul_rn(Tj[j + 2], hr[j + 2]));
                p3 = __fadd_rn(p3, __fmul_rn(Tj[j + 3], hr[j + 3]));
            }
            float s02 = __fadd_rn(p0, p2);
            float s13 = __fadd_rn(p1, p3);
            a = __fadd_rn(s02, s13);
            a = __fadd_rn(a, __fmul_rn(Tj[24], hr[24]));     // scalar tail j=24
        } else {
            a = 0.f;
#pragma unroll
            for (int j = 0; j < DD; ++j)
                a = __fadd_rn(a, __fmul_rn(Tj[j], hr[j]));
        }

        float r2 = 0.f;                                      // h@V: BLAS k-seq FMA
#pragma unroll
        for (int j = 0; j < DD; ++j)
            r2 = fmaf(hr[j], Vcol[j], r2);

        float lin = __fadd_rn(__fadd_rn(qv, r2), bi);        // (xW + hV) + b
        float pre = __fadd_rn(a, lin);                       // a + lin
        hnew = act ? (float)tanh((double)pre) : 0.f;

#pragma unroll
        for (int j = 0; j < DD; ++j)                          // broadcast h within 32-group
            hr[j] = __shfl(hnew, j, 32);

#pragma unroll
        for (int u = 0; u < 7; ++u) cur[u] = nxt[u];
    }

    // logits = h @ out_W.T + out_b ; sigmoid  (BLAS k-seq FMA)
    if (i < NC && b < B) {
        float acc = 0.f;
#pragma unroll
        for (int j = 0; j < DD; ++j)
            acc = fmaf(hr[j], outW[i * DD + j], acc);
        float l = __fadd_rn(acc, outB[i]);
        out[(size_t)b * NC + i] = (float)(1.0 / (1.0 + exp(-(double)l)));
    }
}

extern "C" void kernel_launch(void* const* d_in, const int* in_sizes, int n_in,
                              void* d_out, int out_size, void* d_ws, size_t ws_size,
                              hipStream_t stream)
{
    const int*   words = (const int*)d_in[0];
    const float* emb   = (const float*)d_in[2];
    const float* A     = (const float*)d_in[3];
    const float* W     = (const float*)d_in[4];
    const float* V     = (const float*)d_in[5];
    const float* bias  = (const float*)d_in[6];
    const float* outW  = (const float*)d_in[7];
    const float* outB  = (const float*)d_in[8];
    float* out = (float*)d_out;
    int B = in_sizes[0] / SEQ;

    float* Bmat = (float*)d_ws;                        // 301*768*4 ≈ 0.92 MB
    float* T    = (float*)((char*)d_ws + (1 << 20));   // 50000*704*4 ≈ 140.8 MB

    build_B<<<EE, 256, 0, stream>>>(A, W, Bmat);
    gemm_T<<<dim3((VOCAB + 127) / 128, 6), 256, 0, stream>>>(emb, Bmat, T);
    rnn_scan_np4<<<(B + 7) / 8, 256, 0, stream>>>(words, T, V, bias, outW, outB, out, B);
}

// Round 11
// 512.031 us; speedup vs baseline: 1.7315x; 1.1407x over previous
//
#include <hip/hip_runtime.h>
#include <math.h>

#define VOCAB 50000
#define EE 301
#define DD 25
#define SEQ 128
#define NC 5
#define BROW 768   // Bmat cols (scan-order, zero-padded): col i*28+j = A[i][e][j] (j<25), i*28+25 = W[e][i]
#define NUSE 700   // useful cols: 25 runs x 28 (A-run 25 + q 1 + 2 pad)
#define TROW 704   // T row stride (floats); scan reads i*28 .. i*28+27

// ---------------- Bmat[e][c'] in scan order ----------------
__global__ __launch_bounds__(256) void build_B(
    const float* __restrict__ A, const float* __restrict__ W,
    float* __restrict__ Bmat)
{
    int e = blockIdx.x;
    for (int c = threadIdx.x; c < BROW; c += 256) {
        float v = 0.f;
        if (c < NUSE) {
            int i = c / 28, j = c % 28;
            if (j < 25)       v = A[((size_t)i * EE + e) * DD + j];
            else if (j == 25) v = W[(size_t)e * DD + i];
        }
        Bmat[(size_t)e * BROW + c] = v;
    }
}

// ---------------- T = emb @ Bmat (ascending-k fmaf chain per element) ----------------
// 128x128 tile, 256 threads, 8x8 microtile, split fragments (2-way-max LDS aliasing).
// Software-pipelined: register prefetch of tile k0+1 + double LDS buffer
// -> ONE barrier per k0-step, global latency hidden behind the 16-kk compute.
// launch_bounds(256,2): VGPR budget 256 (the (256,4) cap caused ~950MB spill traffic).
__global__ __launch_bounds__(256, 2) void gemm_T(
    const float* __restrict__ emb,   // [VOCAB][301]
    const float* __restrict__ Bmat,  // [301][BROW]
    float* __restrict__ T)           // [VOCAB][TROW]
{
    __shared__ float As[2][16][132];   // 128m x 16k, double-buffered
    __shared__ float Bs[2][16][132];   // 16k x 128n, double-buffered
    int tid = threadIdx.x;
    int tx = tid & 15, ty = tid >> 4;
    int m0 = blockIdx.x * 128;
    int n0 = blockIdx.y * 128;

    float acc[8][8];
#pragma unroll
    for (int a = 0; a < 8; ++a)
#pragma unroll
        for (int c = 0; c < 8; ++c) acc[a][c] = 0.f;

    float  ar[8];
    float4 br[2];
    int kl0 = tid >> 5, nl0 = (tid & 31) * 4;   // Bs staging coords (2 iters: kl0, kl0+8)

    // --- load tile 0 into regs ---
#pragma unroll
    for (int it = 0; it < 8; ++it) {
        int m = m0 + ty + 16 * it, k = tx;
        ar[it] = (m < VOCAB && k < EE) ? emb[(size_t)m * EE + k] : 0.f;
    }
#pragma unroll
    for (int it = 0; it < 2; ++it) {
        int k = kl0 + 8 * it;
        br[it] = (k < EE) ? *(const float4*)(Bmat + (size_t)k * BROW + n0 + nl0)
                          : make_float4(0.f, 0.f, 0.f, 0.f);
    }
    // --- store tile 0 to LDS[0] ---
#pragma unroll
    for (int it = 0; it < 8; ++it) As[0][tx][ty + 16 * it] = ar[it];
#pragma unroll
    for (int it = 0; it < 2; ++it) *(float4*)(&Bs[0][kl0 + 8 * it][nl0]) = br[it];
    __syncthreads();

    int buf = 0;
    for (int k0 = 0; k0 < EE; k0 += 16) {
        int k1 = k0 + 16;
        bool more = (k1 < EE);
        if (more) {   // issue next tile's global loads (consumed after compute)
#pragma unroll
            for (int it = 0; it < 8; ++it) {
                int m = m0 + ty + 16 * it, k = k1 + tx;
                ar[it] = (m < VOCAB && k < EE) ? emb[(size_t)m * EE + k] : 0.f;
            }
#pragma unroll
            for (int it = 0; it < 2; ++it) {
                int k = k1 + kl0 + 8 * it;
                br[it] = (k < EE) ? *(const float4*)(Bmat + (size_t)k * BROW + n0 + nl0)
                                  : make_float4(0.f, 0.f, 0.f, 0.f);
            }
        }
#pragma unroll
        for (int kk = 0; kk < 16; ++kk) {    // global k strictly ascending
            float4 a0 = *(const float4*)&As[buf][kk][ty * 4];
            float4 a1 = *(const float4*)&As[buf][kk][64 + ty * 4];
            float4 b0 = *(const float4*)&Bs[buf][kk][tx * 4];
            float4 b1 = *(const float4*)&Bs[buf][kk][64 + tx * 4];
            float av[8] = {a0.x, a0.y, a0.z, a0.w, a1.x, a1.y, a1.z, a1.w};
            float bv[8] = {b0.x, b0.y, b0.z, b0.w, b1.x, b1.y, b1.z, b1.w};
#pragma unroll
            for (int a = 0; a < 8; ++a)
#pragma unroll
                for (int c = 0; c < 8; ++c)
                    acc[a][c] = fmaf(av[a], bv[c], acc[a][c]);
        }
        if (more) {   // write next tile to the other buffer; single barrier
            int nb = buf ^ 1;
#pragma unroll
            for (int it = 0; it < 8; ++it) As[nb][tx][ty + 16 * it] = ar[it];
#pragma unroll
            for (int it = 0; it < 2; ++it) *(float4*)(&Bs[nb][kl0 + 8 * it][nl0]) = br[it];
            __syncthreads();
            buf = nb;
        }
    }

    // epilogue: coalesced float4 stores (layout already scan-order)
#pragma unroll
    for (int gi = 0; gi < 2; ++gi) {
#pragma unroll
        for (int r = 0; r < 4; ++r) {
            int m = m0 + gi * 64 + ty * 4 + r;
            if (m < VOCAB) {
                float* row = T + (size_t)m * TROW;
#pragma unroll
                for (int gc = 0; gc < 2; ++gc) {
                    int n = n0 + gc * 64 + tx * 4;
                    if (n < TROW) {
                        int a = gi * 4 + r, c = gc * 4;
                        *(float4*)(row + n) = make_float4(
                            acc[a][c], acc[a][c + 1], acc[a][c + 2], acc[a][c + 3]);
                    }
                }
            }
        }
    }
}

// ---------------- scan: frozen R6/R7 numerics, prefetched + shuffle-based ----------------
__global__ __launch_bounds__(256) void rnn_scan_np4(
    const int*   __restrict__ words,  // [B][SEQ]
    const float* __restrict__ T,      // [VOCAB][TROW]
    const float* __restrict__ V,      // [DD][DD]
    const float* __restrict__ bvec,   // [DD]
    const float* __restrict__ outW,   // [NC][DD]
    const float* __restrict__ outB,   // [NC]
    float* __restrict__ out,          // [B][NC]
    int B)
{
    int tid = threadIdx.x;
    int g = tid >> 5, i = tid & 31;
    int b = blockIdx.x * 8 + g;
    bool act = (i < DD) && (b < B);
    int ii = (i < DD) ? i : (DD - 1);
    int bsafe = (b < B) ? b : 0;
    const int* wr = words + (size_t)bsafe * SEQ;

    float Vcol[DD];
#pragma unroll
    for (int j = 0; j < DD; ++j) Vcol[j] = V[j * DD + ii];   // h@V contracts V[j,i]
    float bi = bvec[ii];

    float hr[DD];
#pragma unroll
    for (int j = 0; j < DD; ++j) hr[j] = 0.f;
    hr[DD - 1] = 1.f;                                        // h0 = e_24

    bool sse = ((b & 3) == 0) && ((i & 3) == 0);
    const float* base = T + (size_t)ii * 28;

    float4 cur[7], nxt[7];
    {
        const float* R = base + (size_t)wr[0] * TROW;
#pragma unroll
        for (int u = 0; u < 7; ++u) cur[u] = *(const float4*)(R + u * 4);
    }

    float hnew = 0.f;
    for (int t = 0; t < SEQ; ++t) {
        int wn = wr[(t + 1 < SEQ) ? t + 1 : t];
        const float* Rn = base + (size_t)wn * TROW;
#pragma unroll
        for (int u = 0; u < 7; ++u) nxt[u] = *(const float4*)(Rn + u * 4);

        float Tj[28];
#pragma unroll
        for (int u = 0; u < 7; ++u) {
            Tj[u * 4 + 0] = cur[u].x; Tj[u * 4 + 1] = cur[u].y;
            Tj[u * 4 + 2] = cur[u].z; Tj[u * 4 + 3] = cur[u].w;
        }
        float qv = Tj[25];

        float a;
        if (sse) {
            float p0 = 0.f, p1 = 0.f, p2 = 0.f, p3 = 0.f;
#pragma unroll
            for (int j = 0; j < 24; j += 4) {
                p0 = __fadd_rn(p0, __fmul_rn(Tj[j],     hr[j]));
                p1 = __fadd_rn(p1, __fmul_rn(Tj[j + 1], hr[j + 1]));
                p2 = __fadd_rn(p2, __fmul_rn(Tj[j + 2], hr[j + 2]));
                p3 = __fadd_rn(p3, __fmul_rn(Tj[j + 3], hr[j + 3]));
            }
            float s02 = __fadd_rn(p0, p2);
            float s13 = __fadd_rn(p1, p3);
            a = __fadd_rn(s02, s13);
            a = __fadd_rn(a, __fmul_rn(Tj[24], hr[24]));     // scalar tail j=24
        } else {
            a = 0.f;
#pragma unroll
            for (int j = 0; j < DD; ++j)
                a = __fadd_rn(a, __fmul_rn(Tj[j], hr[j]));
        }

        float r2 = 0.f;                                      // h@V: BLAS k-seq FMA
#pragma unroll
        for (int j = 0; j < DD; ++j)
            r2 = fmaf(hr[j], Vcol[j], r2);

        float lin = __fadd_rn(__fadd_rn(qv, r2), bi);        // (xW + hV) + b
        float pre = __fadd_rn(a, lin);                       // a + lin
        hnew = act ? (float)tanh((double)pre) : 0.f;

#pragma unroll
        for (int j = 0; j < DD; ++j)                          // broadcast h within 32-group
            hr[j] = __shfl(hnew, j, 32);

#pragma unroll
        for (int u = 0; u < 7; ++u) cur[u] = nxt[u];
    }

    // logits = h @ out_W.T + out_b ; sigmoid  (BLAS k-seq FMA)
    if (i < NC && b < B) {
        float acc = 0.f;
#pragma unroll
        for (int j = 0; j < DD; ++j)
            acc = fmaf(hr[j], outW[i * DD + j], acc);
        float l = __fadd_rn(acc, outB[i]);
        out[(size_t)b * NC + i] = (float)(1.0 / (1.0 + exp(-(double)l)));
    }
}

extern "C" void kernel_launch(void* const* d_in, const int* in_sizes, int n_in,
                              void* d_out, int out_size, void* d_ws, size_t ws_size,
                              hipStream_t stream)
{
    const int*   words = (const int*)d_in[0];
    const float* emb   = (const float*)d_in[2];
    const float* A     = (const float*)d_in[3];
    const float* W     = (const float*)d_in[4];
    const float* V     = (const float*)d_in[5];
    const float* bias  = (const float*)d_in[6];
    const float* outW  = (const float*)d_in[7];
    const float* outB  = (const float*)d_in[8];
    float* out = (float*)d_out;
    int B = in_sizes[0] / SEQ;

    float* Bmat = (float*)d_ws;                        // 301*768*4 ≈ 0.92 MB
    float* T    = (float*)((char*)d_ws + (1 << 20));   // 50000*704*4 ≈ 140.8 MB

    build_B<<<EE, 256, 0, stream>>>(A, W, Bmat);
    gemm_T<<<dim3((VOCAB + 127) / 128, 6), 256, 0, stream>>>(emb, Bmat, T);
    rnn_scan_np4<<<(B + 7) / 8, 256, 0, stream>>>(words, T, V, bias, outW, outB, out, B);
}

// Round 12
// 511.333 us; speedup vs baseline: 1.7339x; 1.0014x over previous
//
#include <hip/hip_runtime.h>
#include <math.h>

#define VOCAB 50000
#define EE 301
#define KP 304     // padded K (multiple of 16; rows EE..KP-1 are zeros)
#define DD 25
#define SEQ 128
#define NC 5
#define BROW 768   // Bmat cols (scan-order, zero-padded): col i*28+j = A[i][e][j] (j<25), i*28+25 = W[e][i]
#define NUSE 700
#define TROW 704   // T row stride (floats); scan reads i*28 .. i*28+27
#define EMT 50048  // embT row stride (m padded to 128-multiple)

// async global->LDS DMA, 16B per lane, lane i lands at ldsbase + i*16
#define GLOAD_LDS16(g, l) __builtin_amdgcn_global_load_lds( \
    (const __attribute__((address_space(1))) void*)(g),     \
    (__attribute__((address_space(3))) void*)(l), 16, 0, 0)

// ---------------- Bmat[e][c'] in scan order; rows EE..KP-1 zero ----------------
__global__ __launch_bounds__(256) void build_B(
    const float* __restrict__ A, const float* __restrict__ W,
    float* __restrict__ Bmat)
{
    int e = blockIdx.x;
    for (int c = threadIdx.x; c < BROW; c += 256) {
        float v = 0.f;
        if (e < EE && c < NUSE) {
            int i = c / 28, j = c % 28;
            if (j < 25)       v = A[((size_t)i * EE + e) * DD + j];
            else if (j == 25) v = W[(size_t)e * DD + i];
        }
        Bmat[(size_t)e * BROW + c] = v;
    }
}

// ---------------- embT[k][m] = emb[m][k] (pure copy; zeros for k>=EE, m>=VOCAB) ----------------
__global__ __launch_bounds__(256) void transpose_emb(
    const float* __restrict__ emb, float* __restrict__ embT)
{
    __shared__ float t[64][65];
    int m0 = blockIdx.x * 64, k0 = blockIdx.y * 64;
    int tx = threadIdx.x & 63, ty = threadIdx.x >> 6;   // ty 0..3
#pragma unroll
    for (int it = 0; it < 16; ++it) {
        int m = m0 + ty * 16 + it;
        int k = k0 + tx;
        t[tx][ty * 16 + it] = (m < VOCAB && k < EE) ? emb[(size_t)m * EE + k] : 0.f;
    }
    __syncthreads();
#pragma unroll
    for (int it = 0; it < 16; ++it) {
        int kl = ty * 16 + it;
        int k = k0 + kl;
        if (k < KP) embT[(size_t)k * EMT + m0 + tx] = t[kl][tx];
    }
}

// ---------------- fast GEMM: global_load_lds staging, double LDS buffer ----------------
// 128x128 tile, 8x8 microtile; ascending-k fmaf chain per element (k 0..303, zero tail).
__global__ __launch_bounds__(256, 2) void gemm_T2(
    const float* __restrict__ embT,  // [KP][EMT] k-major
    const float* __restrict__ Bmat,  // [KP][BROW]
    float* __restrict__ T)           // [VOCAB][TROW]
{
    __shared__ float As[2][16][128];
    __shared__ float Bs[2][16][128];
    int tid = threadIdx.x;
    int tx = tid & 15, ty = tid >> 4;
    int m0 = blockIdx.x * 128, n0 = blockIdx.y * 128;
    int wave = tid >> 6, lane = tid & 63;
    int krow = lane >> 5;            // 0/1: second k-row of this DMA instr
    int col4 = (lane & 31) * 4;      // 32 lanes x 16B = one 512B k-row segment

    float acc[8][8];
#pragma unroll
    for (int a = 0; a < 8; ++a)
#pragma unroll
        for (int c = 0; c < 8; ++c) acc[a][c] = 0.f;

    auto dma_tile = [&](int k0, int buf) {
#pragma unroll
        for (int j = 0; j < 2; ++j) {
            int r0 = wave * 4 + j * 2;               // rows r0, r0+1
            int k = k0 + r0 + krow;
            GLOAD_LDS16(embT + (size_t)k * EMT + m0 + col4, &As[buf][r0][0]);
            GLOAD_LDS16(Bmat + (size_t)k * BROW + n0 + col4, &Bs[buf][r0][0]);
        }
    };

    dma_tile(0, 0);
    __syncthreads();                 // drains vmcnt -> tile 0 in LDS

    int buf = 0;
    for (int k0 = 0; k0 < KP; k0 += 16) {
        if (k0 + 16 < KP) dma_tile(k0 + 16, buf ^ 1);   // async, lands during compute
#pragma unroll
        for (int kk = 0; kk < 16; ++kk) {               // global k strictly ascending
            float4 a0 = *(const float4*)&As[buf][kk][ty * 4];
            float4 a1 = *(const float4*)&As[buf][kk][64 + ty * 4];
            float4 b0 = *(const float4*)&Bs[buf][kk][tx * 4];
            float4 b1 = *(const float4*)&Bs[buf][kk][64 + tx * 4];
            float av[8] = {a0.x, a0.y, a0.z, a0.w, a1.x, a1.y, a1.z, a1.w};
            float bv[8] = {b0.x, b0.y, b0.z, b0.w, b1.x, b1.y, b1.z, b1.w};
#pragma unroll
            for (int a = 0; a < 8; ++a)
#pragma unroll
                for (int c = 0; c < 8; ++c)
                    acc[a][c] = fmaf(av[a], bv[c], acc[a][c]);
        }
        __syncthreads();             // waits DMA (vmcnt) + all reads of buf done
        buf ^= 1;
    }

    // epilogue: coalesced float4 stores (layout already scan-order)
#pragma unroll
    for (int gi = 0; gi < 2; ++gi) {
#pragma unroll
        for (int r = 0; r < 4; ++r) {
            int m = m0 + gi * 64 + ty * 4 + r;
            if (m < VOCAB) {
                float* row = T + (size_t)m * TROW;
#pragma unroll
                for (int gc = 0; gc < 2; ++gc) {
                    int n = n0 + gc * 64 + tx * 4;
                    if (n < TROW) {
                        int a = gi * 4 + r, c = gc * 4;
                        *(float4*)(row + n) = make_float4(
                            acc[a][c], acc[a][c + 1], acc[a][c + 2], acc[a][c + 3]);
                    }
                }
            }
        }
    }
}

// ---------------- fallback GEMM (R11): register-prefetch pipeline ----------------
__global__ __launch_bounds__(256, 2) void gemm_T(
    const float* __restrict__ emb, const float* __restrict__ Bmat,
    float* __restrict__ T)
{
    __shared__ float As[2][16][132];
    __shared__ float Bs[2][16][132];
    int tid = threadIdx.x;
    int tx = tid & 15, ty = tid >> 4;
    int m0 = blockIdx.x * 128, n0 = blockIdx.y * 128;
    float acc[8][8];
#pragma unroll
    for (int a = 0; a < 8; ++a)
#pragma unroll
        for (int c = 0; c < 8; ++c) acc[a][c] = 0.f;
    float ar[8]; float4 br[2];
    int kl0 = tid >> 5, nl0 = (tid & 31) * 4;
#pragma unroll
    for (int it = 0; it < 8; ++it) {
        int m = m0 + ty + 16 * it, k = tx;
        ar[it] = (m < VOCAB && k < EE) ? emb[(size_t)m * EE + k] : 0.f;
    }
#pragma unroll
    for (int it = 0; it < 2; ++it) {
        int k = kl0 + 8 * it;
        br[it] = (k < EE) ? *(const float4*)(Bmat + (size_t)k * BROW + n0 + nl0)
                          : make_float4(0.f, 0.f, 0.f, 0.f);
    }
#pragma unroll
    for (int it = 0; it < 8; ++it) As[0][tx][ty + 16 * it] = ar[it];
#pragma unroll
    for (int it = 0; it < 2; ++it) *(float4*)(&Bs[0][kl0 + 8 * it][nl0]) = br[it];
    __syncthreads();
    int buf = 0;
    for (int k0 = 0; k0 < EE; k0 += 16) {
        int k1 = k0 + 16;
        bool more = (k1 < EE);
        if (more) {
#pragma unroll
            for (int it = 0; it < 8; ++it) {
                int m = m0 + ty + 16 * it, k = k1 + tx;
                ar[it] = (m < VOCAB && k < EE) ? emb[(size_t)m * EE + k] : 0.f;
            }
#pragma unroll
            for (int it = 0; it < 2; ++it) {
                int k = k1 + kl0 + 8 * it;
                br[it] = (k < EE) ? *(const float4*)(Bmat + (size_t)k * BROW + n0 + nl0)
                                  : make_float4(0.f, 0.f, 0.f, 0.f);
            }
        }
#pragma unroll
        for (int kk = 0; kk < 16; ++kk) {
            float4 a0 = *(const float4*)&As[buf][kk][ty * 4];
            float4 a1 = *(const float4*)&As[buf][kk][64 + ty * 4];
            float4 b0 = *(const float4*)&Bs[buf][kk][tx * 4];
            float4 b1 = *(const float4*)&Bs[buf][kk][64 + tx * 4];
            float av[8] = {a0.x, a0.y, a0.z, a0.w, a1.x, a1.y, a1.z, a1.w};
            float bv[8] = {b0.x, b0.y, b0.z, b0.w, b1.x, b1.y, b1.z, b1.w};
#pragma unroll
            for (int a = 0; a < 8; ++a)
#pragma unroll
                for (int c = 0; c < 8; ++c)
                    acc[a][c] = fmaf(av[a], bv[c], acc[a][c]);
        }
        if (more) {
            int nb = buf ^ 1;
#pragma unroll
            for (int it = 0; it < 8; ++it) As[nb][tx][ty + 16 * it] = ar[it];
#pragma unroll
            for (int it = 0; it < 2; ++it) *(float4*)(&Bs[nb][kl0 + 8 * it][nl0]) = br[it];
            __syncthreads();
            buf = nb;
        }
    }
#pragma unroll
    for (int gi = 0; gi < 2; ++gi) {
#pragma unroll
        for (int r = 0; r < 4; ++r) {
            int m = m0 + gi * 64 + ty * 4 + r;
            if (m < VOCAB) {
                float* row = T + (size_t)m * TROW;
#pragma unroll
                for (int gc = 0; gc < 2; ++gc) {
                    int n = n0 + gc * 64 + tx * 4;
                    if (n < TROW) {
                        int a = gi * 4 + r, c = gc * 4;
                        *(float4*)(row + n) = make_float4(
                            acc[a][c], acc[a][c + 1], acc[a][c + 2], acc[a][c + 3]);
                    }
                }
            }
        }
    }
}

// ---------------- scan: frozen numerics, depth-2 prefetch (3 rotating buffers) ----------------
__global__ __launch_bounds__(256) void rnn_scan_np5(
    const int*   __restrict__ words,
    const float* __restrict__ T,
    const float* __restrict__ V,
    const float* __restrict__ bvec,
    const float* __restrict__ outW,
    const float* __restrict__ outB,
    float* __restrict__ out,
    int B)
{
    int tid = threadIdx.x;
    int g = tid >> 5, i = tid & 31;
    int b = blockIdx.x * 8 + g;
    bool act = (i < DD) && (b < B);
    int ii = (i < DD) ? i : (DD - 1);
    int bsafe = (b < B) ? b : 0;
    const int* wr = words + (size_t)bsafe * SEQ;

    float Vcol[DD];
#pragma unroll
    for (int j = 0; j < DD; ++j) Vcol[j] = V[j * DD + ii];
    float bi = bvec[ii];

    float hr[DD];
#pragma unroll
    for (int j = 0; j < DD; ++j) hr[j] = 0.f;
    hr[DD - 1] = 1.f;                // h0 = e_24

    bool sse = ((b & 3) == 0) && ((i & 3) == 0);
    const float* base = T + (size_t)ii * 28;

    float4 A0[7], A1[7], A2[7];
    auto LD = [&](float4* dst, int t) {
        const float* R = base + (size_t)wr[t] * TROW;
#pragma unroll
        for (int u = 0; u < 7; ++u) dst[u] = *(const float4*)(R + u * 4);
    };

    float hnew = 0.f;
    auto STEP = [&](const float4* C) {
        float Tj[28];
#pragma unroll
        for (int u = 0; u < 7; ++u) {
            Tj[u * 4 + 0] = C[u].x; Tj[u * 4 + 1] = C[u].y;
            Tj[u * 4 + 2] = C[u].z; Tj[u * 4 + 3] = C[u].w;
        }
        float qv = Tj[25];
        float a;
        if (sse) {
            float p0 = 0.f, p1 = 0.f, p2 = 0.f, p3 = 0.f;
#pragma unroll
            for (int j = 0; j < 24; j += 4) {
                p0 = __fadd_rn(p0, __fmul_rn(Tj[j],     hr[j]));
                p1 = __fadd_rn(p1, __fmul_rn(Tj[j + 1], hr[j + 1]));
                p2 = __fadd_rn(p2, __fmul_rn(Tj[j + 2], hr[j + 2]));
                p3 = __fadd_rn(p3, __fmul_rn(Tj[j + 3], hr[j + 3]));
            }
            float s02 = __fadd_rn(p0, p2);
            float s13 = __fadd_rn(p1, p3);
            a = __fadd_rn(s02, s13);
            a = __fadd_rn(a, __fmul_rn(Tj[24], hr[24]));
        } else {
            a = 0.f;
#pragma unroll
            for (int j = 0; j < DD; ++j)
                a = __fadd_rn(a, __fmul_rn(Tj[j], hr[j]));
        }
        float r2 = 0.f;
#pragma unroll
        for (int j = 0; j < DD; ++j)
            r2 = fmaf(hr[j], Vcol[j], r2);
        float lin = __fadd_rn(__fadd_rn(qv, r2), bi);
        float pre = __fadd_rn(a, lin);
        hnew = act ? (float)tanh((double)pre) : 0.f;
#pragma unroll
        for (int j = 0; j < DD; ++j)
            hr[j] = __shfl(hnew, j, 32);
    };

    LD(A0, 0);
    LD(A1, 1);
    for (int t = 0; t + 2 < SEQ; t += 3) {   // t = 0,3,...,123
        LD(A2, t + 2); STEP(A0);
        LD(A0, t + 3); STEP(A1);
        LD(A1, t + 4); STEP(A2);
    }
    STEP(A0);   // t = 126
    STEP(A1);   // t = 127

    if (i < NC && b < B) {
        float acc = 0.f;
#pragma unroll
        for (int j = 0; j < DD; ++j)
            acc = fmaf(hr[j], outW[i * DD + j], acc);
        float l = __fadd_rn(acc, outB[i]);
        out[(size_t)b * NC + i] = (float)(1.0 / (1.0 + exp(-(double)l)));
    }
}

extern "C" void kernel_launch(void* const* d_in, const int* in_sizes, int n_in,
                              void* d_out, int out_size, void* d_ws, size_t ws_size,
                              hipStream_t stream)
{
    const int*   words = (const int*)d_in[0];
    const float* emb   = (const float*)d_in[2];
    const float* A     = (const float*)d_in[3];
    const float* W     = (const float*)d_in[4];
    const float* V     = (const float*)d_in[5];
    const float* bias  = (const float*)d_in[6];
    const float* outW  = (const float*)d_in[7];
    const float* outB  = (const float*)d_in[8];
    float* out = (float*)d_out;
    int B = in_sizes[0] / SEQ;

    const size_t T_OFF    = (size_t)1 << 20;                 // Bmat: 304*768*4 = 0.93 MB
    const size_t EMBT_OFF = (size_t)144 << 20;               // T: 50000*704*4 = 140.8 MB
    const size_t NEED     = EMBT_OFF + (size_t)KP * EMT * 4; // + embT 60.9 MB ≈ 212 MB
    float* Bmat = (float*)d_ws;
    float* T    = (float*)((char*)d_ws + T_OFF);
    float* embT = (float*)((char*)d_ws + EMBT_OFF);

    build_B<<<KP, 256, 0, stream>>>(A, W, Bmat);
    if (ws_size >= NEED) {
        transpose_emb<<<dim3(EMT / 64, (KP + 63) / 64), 256, 0, stream>>>(emb, embT);
        gemm_T2<<<dim3((VOCAB + 127) / 128, 6), 256, 0, stream>>>(embT, Bmat, T);
    } else {
        gemm_T<<<dim3((VOCAB + 127) / 128, 6), 256, 0, stream>>>(emb, Bmat, T);
    }
    rnn_scan_np5<<<(B + 7) / 8, 256, 0, stream>>>(words, T, V, bias, outW, outB, out, B);
}

// Round 13
// 499.025 us; speedup vs baseline: 1.7767x; 1.0247x over previous
//
#include <hip/hip_runtime.h>
#include <math.h>

#define VOCAB 50000
#define EE 301
#define KP 304     // padded K (multiple of 16; rows EE..KP-1 are zeros)
#define DD 25
#define SEQ 128
#define NC 5
#define BROW 768   // Bmat cols (scan-order, zero-padded): col i*28+j = A[i][e][j] (j<25), i*28+25 = W[e][i]
#define NUSE 700
#define TROW 704   // T row stride (floats); scan reads i*28 .. i*28+27
#define EMT 50048  // embT row stride

// async global->LDS DMA, 16B per lane, lane i lands at ldsbase + i*16
#define GLOAD_LDS16(g, l) __builtin_amdgcn_global_load_lds( \
    (const __attribute__((address_space(1))) void*)(g),     \
    (__attribute__((address_space(3))) void*)(l), 16, 0, 0)

// ---------------- Bmat[e][c'] in scan order; rows EE..KP-1 zero ----------------
__global__ __launch_bounds__(256) void build_B(
    const float* __restrict__ A, const float* __restrict__ W,
    float* __restrict__ Bmat)
{
    int e = blockIdx.x;
    for (int c = threadIdx.x; c < BROW; c += 256) {
        float v = 0.f;
        if (e < EE && c < NUSE) {
            int i = c / 28, j = c % 28;
            if (j < 25)       v = A[((size_t)i * EE + e) * DD + j];
            else if (j == 25) v = W[(size_t)e * DD + i];
        }
        Bmat[(size_t)e * BROW + c] = v;
    }
}

// ---------------- embT[k][m] = emb[m][k] (pure copy; zeros for k>=EE, m>=VOCAB) ----------------
__global__ __launch_bounds__(256) void transpose_emb(
    const float* __restrict__ emb, float* __restrict__ embT)
{
    __shared__ float t[64][65];
    int m0 = blockIdx.x * 64, k0 = blockIdx.y * 64;
    int tx = threadIdx.x & 63, ty = threadIdx.x >> 6;   // ty 0..3
#pragma unroll
    for (int it = 0; it < 16; ++it) {
        int m = m0 + ty * 16 + it;
        int k = k0 + tx;
        t[tx][ty * 16 + it] = (m < VOCAB && k < EE) ? emb[(size_t)m * EE + k] : 0.f;
    }
    __syncthreads();
#pragma unroll
    for (int it = 0; it < 16; ++it) {
        int kl = ty * 16 + it;
        int k = k0 + kl;
        if (k < KP) embT[(size_t)k * EMT + m0 + tx] = t[kl][tx];
    }
}

// ---------------- GEMM v3: 128m x 256n tile, 8x16 microtile, DMA staging ----------------
// ascending-k fmaf chain per element (k 0..303, zero tail) -- bit-frozen.
__global__ __launch_bounds__(256, 1) void gemm_T3(
    const float* __restrict__ embT,  // [KP][EMT] k-major
    const float* __restrict__ Bmat,  // [KP][BROW]
    float* __restrict__ T)           // [VOCAB][TROW]
{
    __shared__ float As[2][16][128];   // 16 KB
    __shared__ float Bs[2][16][256];   // 32 KB
    int tid = threadIdx.x;
    int tx = tid & 15, ty = tid >> 4;
    int m0 = blockIdx.x * 128, n0 = blockIdx.y * 256;
    int wave = tid >> 6, lane = tid & 63;
    int krow = lane >> 5;
    int col4 = (lane & 31) * 4;

    float acc[8][16];
#pragma unroll
    for (int a = 0; a < 8; ++a)
#pragma unroll
        for (int c = 0; c < 16; ++c) acc[a][c] = 0.f;

    auto dma_tile = [&](int k0, int buf) {
#pragma unroll
        for (int j = 0; j < 2; ++j) {          // As: 2 instr/wave, 2 rows each
            int r0 = wave * 4 + j * 2;
            int k = k0 + r0 + krow;
            GLOAD_LDS16(embT + (size_t)k * EMT + m0 + col4, &As[buf][r0][0]);
        }
#pragma unroll
        for (int j = 0; j < 4; ++j) {          // Bs: 4 instr/wave, 1 row each
            int r = wave * 4 + j;
            int k = k0 + r;
            GLOAD_LDS16(Bmat + (size_t)k * BROW + n0 + lane * 4, &Bs[buf][r][0]);
        }
    };

    dma_tile(0, 0);
    __syncthreads();

    int buf = 0;
    for (int k0 = 0; k0 < KP; k0 += 16) {
        if (k0 + 16 < KP) dma_tile(k0 + 16, buf ^ 1);
#pragma unroll
        for (int kk = 0; kk < 16; ++kk) {      // global k strictly ascending
            float4 a0 = *(const float4*)&As[buf][kk][ty * 4];
            float4 a1 = *(const float4*)&As[buf][kk][64 + ty * 4];
            float4 b0 = *(const float4*)&Bs[buf][kk][tx * 4];
            float4 b1 = *(const float4*)&Bs[buf][kk][64 + tx * 4];
            float4 b2 = *(const float4*)&Bs[buf][kk][128 + tx * 4];
            float4 b3 = *(const float4*)&Bs[buf][kk][192 + tx * 4];
            float av[8]  = {a0.x, a0.y, a0.z, a0.w, a1.x, a1.y, a1.z, a1.w};
            float bv[16] = {b0.x, b0.y, b0.z, b0.w, b1.x, b1.y, b1.z, b1.w,
                            b2.x, b2.y, b2.z, b2.w, b3.x, b3.y, b3.z, b3.w};
#pragma unroll
            for (int a = 0; a < 8; ++a)
#pragma unroll
                for (int c = 0; c < 16; ++c)
                    acc[a][c] = fmaf(av[a], bv[c], acc[a][c]);
        }
        __syncthreads();
        buf ^= 1;
    }

    // epilogue: coalesced float4 stores (layout already scan-order)
#pragma unroll
    for (int gi = 0; gi < 2; ++gi) {
#pragma unroll
        for (int r = 0; r < 4; ++r) {
            int m = m0 + gi * 64 + ty * 4 + r;
            if (m < VOCAB) {
                float* row = T + (size_t)m * TROW;
#pragma unroll
                for (int gc = 0; gc < 4; ++gc) {
                    int n = n0 + gc * 64 + tx * 4;
                    if (n < TROW) {
                        int a = gi * 4 + r, c = gc * 4;
                        *(float4*)(row + n) = make_float4(
                            acc[a][c], acc[a][c + 1], acc[a][c + 2], acc[a][c + 3]);
                    }
                }
            }
        }
    }
}

// ---------------- fallback GEMM (R11): register-prefetch pipeline ----------------
__global__ __launch_bounds__(256, 2) void gemm_T(
    const float* __restrict__ emb, const float* __restrict__ Bmat,
    float* __restrict__ T)
{
    __shared__ float As[2][16][132];
    __shared__ float Bs[2][16][132];
    int tid = threadIdx.x;
    int tx = tid & 15, ty = tid >> 4;
    int m0 = blockIdx.x * 128, n0 = blockIdx.y * 128;
    float acc[8][8];
#pragma unroll
    for (int a = 0; a < 8; ++a)
#pragma unroll
        for (int c = 0; c < 8; ++c) acc[a][c] = 0.f;
    float ar[8]; float4 br[2];
    int kl0 = tid >> 5, nl0 = (tid & 31) * 4;
#pragma unroll
    for (int it = 0; it < 8; ++it) {
        int m = m0 + ty + 16 * it, k = tx;
        ar[it] = (m < VOCAB && k < EE) ? emb[(size_t)m * EE + k] : 0.f;
    }
#pragma unroll
    for (int it = 0; it < 2; ++it) {
        int k = kl0 + 8 * it;
        br[it] = (k < EE) ? *(const float4*)(Bmat + (size_t)k * BROW + n0 + nl0)
                          : make_float4(0.f, 0.f, 0.f, 0.f);
    }
#pragma unroll
    for (int it = 0; it < 8; ++it) As[0][tx][ty + 16 * it] = ar[it];
#pragma unroll
    for (int it = 0; it < 2; ++it) *(float4*)(&Bs[0][kl0 + 8 * it][nl0]) = br[it];
    __syncthreads();
    int buf = 0;
    for (int k0 = 0; k0 < EE; k0 += 16) {
        int k1 = k0 + 16;
        bool more = (k1 < EE);
        if (more) {
#pragma unroll
            for (int it = 0; it < 8; ++it) {
                int m = m0 + ty + 16 * it, k = k1 + tx;
                ar[it] = (m < VOCAB && k < EE) ? emb[(size_t)m * EE + k] : 0.f;
            }
#pragma unroll
            for (int it = 0; it < 2; ++it) {
                int k = k1 + kl0 + 8 * it;
                br[it] = (k < EE) ? *(const float4*)(Bmat + (size_t)k * BROW + n0 + nl0)
                                  : make_float4(0.f, 0.f, 0.f, 0.f);
            }
        }
#pragma unroll
        for (int kk = 0; kk < 16; ++kk) {
            float4 a0 = *(const float4*)&As[buf][kk][ty * 4];
            float4 a1 = *(const float4*)&As[buf][kk][64 + ty * 4];
            float4 b0 = *(const float4*)&Bs[buf][kk][tx * 4];
            float4 b1 = *(const float4*)&Bs[buf][kk][64 + tx * 4];
            float av[8] = {a0.x, a0.y, a0.z, a0.w, a1.x, a1.y, a1.z, a1.w};
            float bv[8] = {b0.x, b0.y, b0.z, b0.w, b1.x, b1.y, b1.z, b1.w};
#pragma unroll
            for (int a = 0; a < 8; ++a)
#pragma unroll
                for (int c = 0; c < 8; ++c)
                    acc[a][c] = fmaf(av[a], bv[c], acc[a][c]);
        }
        if (more) {
            int nb = buf ^ 1;
#pragma unroll
            for (int it = 0; it < 8; ++it) As[nb][tx][ty + 16 * it] = ar[it];
#pragma unroll
            for (int it = 0; it < 2; ++it) *(float4*)(&Bs[nb][kl0 + 8 * it][nl0]) = br[it];
            __syncthreads();
            buf = nb;
        }
    }
#pragma unroll
    for (int gi = 0; gi < 2; ++gi) {
#pragma unroll
        for (int r = 0; r < 4; ++r) {
            int m = m0 + gi * 64 + ty * 4 + r;
            if (m < VOCAB) {
                float* row = T + (size_t)m * TROW;
#pragma unroll
                for (int gc = 0; gc < 2; ++gc) {
                    int n = n0 + gc * 64 + tx * 4;
                    if (n < TROW) {
                        int a = gi * 4 + r, c = gc * 4;
                        *(float4*)(row + n) = make_float4(
                            acc[a][c], acc[a][c + 1], acc[a][c + 2], acc[a][c + 3]);
                    }
                }
            }
        }
    }
}

// ---------------- scan: frozen numerics, depth-3 prefetch (4 rotating buffers) ----------------
__global__ __launch_bounds__(256, 1) void rnn_scan_np6(
    const int*   __restrict__ words,
    const float* __restrict__ T,
    const float* __restrict__ V,
    const float* __restrict__ bvec,
    const float* __restrict__ outW,
    const float* __restrict__ outB,
    float* __restrict__ out,
    int B)
{
    int tid = threadIdx.x;
    int g = tid >> 5, i = tid & 31;
    int b = blockIdx.x * 8 + g;
    bool act = (i < DD) && (b < B);
    int ii = (i < DD) ? i : (DD - 1);
    int bsafe = (b < B) ? b : 0;
    const int* wr = words + (size_t)bsafe * SEQ;

    float Vcol[DD];
#pragma unroll
    for (int j = 0; j < DD; ++j) Vcol[j] = V[j * DD + ii];
    float bi = bvec[ii];

    float hr[DD];
#pragma unroll
    for (int j = 0; j < DD; ++j) hr[j] = 0.f;
    hr[DD - 1] = 1.f;                // h0 = e_24

    bool sse = ((b & 3) == 0) && ((i & 3) == 0);
    const float* base = T + (size_t)ii * 28;

    float4 A0[7], A1[7], A2[7], A3[7];
    auto LD = [&](float4* dst, int t) {
        const float* R = base + (size_t)wr[t] * TROW;
#pragma unroll
        for (int u = 0; u < 7; ++u) dst[u] = *(const float4*)(R + u * 4);
    };

    float hnew = 0.f;
    auto STEP = [&](const float4* C) {
        float Tj[28];
#pragma unroll
        for (int u = 0; u < 7; ++u) {
            Tj[u * 4 + 0] = C[u].x; Tj[u * 4 + 1] = C[u].y;
            Tj[u * 4 + 2] = C[u].z; Tj[u * 4 + 3] = C[u].w;
        }
        float qv = Tj[25];
        float a;
        if (sse) {
            float p0 = 0.f, p1 = 0.f, p2 = 0.f, p3 = 0.f;
#pragma unroll
            for (int j = 0; j < 24; j += 4) {
                p0 = __fadd_rn(p0, __fmul_rn(Tj[j],     hr[j]));
                p1 = __fadd_rn(p1, __fmul_rn(Tj[j + 1], hr[j + 1]));
                p2 = __fadd_rn(p2, __fmul_rn(Tj[j + 2], hr[j + 2]));
                p3 = __fadd_rn(p3, __fmul_rn(Tj[j + 3], hr[j + 3]));
            }
            float s02 = __fadd_rn(p0, p2);
            float s13 = __fadd_rn(p1, p3);
            a = __fadd_rn(s02, s13);
            a = __fadd_rn(a, __fmul_rn(Tj[24], hr[24]));
        } else {
            a = 0.f;
#pragma unroll
            for (int j = 0; j < DD; ++j)
                a = __fadd_rn(a, __fmul_rn(Tj[j], hr[j]));
        }
        float r2 = 0.f;
#pragma unroll
        for (int j = 0; j < DD; ++j)
            r2 = fmaf(hr[j], Vcol[j], r2);
        float lin = __fadd_rn(__fadd_rn(qv, r2), bi);
        float pre = __fadd_rn(a, lin);
        hnew = act ? (float)tanh((double)pre) : 0.f;
#pragma unroll
        for (int j = 0; j < DD; ++j)
            hr[j] = __shfl(hnew, j, 32);
    };

    LD(A0, 0); LD(A1, 1); LD(A2, 2);
    int t = 0;
    for (; t + 6 < SEQ; t += 4) {            // t = 0,4,...,120
        LD(A3, t + 3); STEP(A0);
        LD(A0, t + 4); STEP(A1);
        LD(A1, t + 5); STEP(A2);
        LD(A2, t + 6); STEP(A3);
    }
    // t == 124: A0<-124, A1<-125, A2<-126 loaded; steps 124..127 remain
    LD(A3, 127);
    STEP(A0); STEP(A1); STEP(A2); STEP(A3);

    if (i < NC && b < B) {
        float acc = 0.f;
#pragma unroll
        for (int j = 0; j < DD; ++j)
            acc = fmaf(hr[j], outW[i * DD + j], acc);
        float l = __fadd_rn(acc, outB[i]);
        out[(size_t)b * NC + i] = (float)(1.0 / (1.0 + exp(-(double)l)));
    }
}

extern "C" void kernel_launch(void* const* d_in, const int* in_sizes, int n_in,
                              void* d_out, int out_size, void* d_ws, size_t ws_size,
                              hipStream_t stream)
{
    const int*   words = (const int*)d_in[0];
    const float* emb   = (const float*)d_in[2];
    const float* A     = (const float*)d_in[3];
    const float* W     = (const float*)d_in[4];
    const float* V     = (const float*)d_in[5];
    const float* bias  = (const float*)d_in[6];
    const float* outW  = (const float*)d_in[7];
    const float* outB  = (const float*)d_in[8];
    float* out = (float*)d_out;
    int B = in_sizes[0] / SEQ;

    const size_t T_OFF    = (size_t)1 << 20;                 // Bmat: 304*768*4 = 0.93 MB
    const size_t EMBT_OFF = (size_t)144 << 20;               // T: 50000*704*4 = 140.8 MB
    const size_t NEED     = EMBT_OFF + (size_t)KP * EMT * 4; // + embT 60.9 MB ≈ 212 MB
    float* Bmat = (float*)d_ws;
    float* T    = (float*)((char*)d_ws + T_OFF);
    float* embT = (float*)((char*)d_ws + EMBT_OFF);

    build_B<<<KP, 256, 0, stream>>>(A, W, Bmat);
    if (ws_size >= NEED) {
        transpose_emb<<<dim3(EMT / 64, (KP + 63) / 64), 256, 0, stream>>>(emb, embT);
        gemm_T3<<<dim3((VOCAB + 127) / 128, 3), 256, 0, stream>>>(embT, Bmat, T);
    } else {
        gemm_T<<<dim3((VOCAB + 127) / 128, 6), 256, 0, stream>>>(emb, Bmat, T);
    }
    rnn_scan_np6<<<(B + 7) / 8, 256, 0, stream>>>(words, T, V, bias, outW, outB, out, B);
}